// Round 11
// baseline (442.268 us; speedup 1.0000x reference)
//
#include <hip/hip_runtime.h>

#define EPS_BN 1e-5f
#define C 128
#define CG 32     // float4 groups per 128-channel row
#define CAP 6144  // per-bucket edge capacity in LDS (mean 4096, sigma ~64)
#define NBLK 256  // partition blocks
#define CHK 16    // src-chunk slots per bucket (chunk = src >> 13, 2MB of y each)

typedef __attribute__((ext_vector_type(8))) short bf16x8;
typedef __attribute__((ext_vector_type(4))) float f32x4;

__device__ inline unsigned bf16_rne(float f) {
  unsigned u = __float_as_uint(f);
  return (u + 0x7FFFu + ((u >> 16) & 1u)) >> 16;
}
__device__ inline float bf16_f(unsigned h) { return __uint_as_float(h << 16); }

// ---------------- init: zero BN accumulators ----------------------------------
__global__ void k_init(float* __restrict__ sums) {
  int i = blockIdx.x * blockDim.x + threadIdx.x;
  if (i < 256) sums[i] = 0.0f;
}

// ---------------- column sum / sumsq over rows --------------------------------
__global__ void k_stats(const float4* __restrict__ x4, float* __restrict__ sums, int n) {
  __shared__ float4 s_s[256];
  __shared__ float4 s_q[256];
  int t = threadIdx.x;
  int cg = t & 31;
  int rl = t >> 5;
  float4 s = make_float4(0.f, 0.f, 0.f, 0.f);
  float4 q = make_float4(0.f, 0.f, 0.f, 0.f);
  for (int r = blockIdx.x * 8 + rl; r < n; r += gridDim.x * 8) {
    float4 v = x4[(size_t)r * CG + cg];
    s.x += v.x; s.y += v.y; s.z += v.z; s.w += v.w;
    q.x += v.x * v.x; q.y += v.y * v.y; q.z += v.z * v.z; q.w += v.w * v.w;
  }
  s_s[t] = s; s_q[t] = q;
  __syncthreads();
  if (t < 32) {
    for (int j = 1; j < 8; ++j) {
      float4 a = s_s[t + 32 * j];
      float4 b = s_q[t + 32 * j];
      s.x += a.x; s.y += a.y; s.z += a.z; s.w += a.w;
      q.x += b.x; q.y += b.y; q.z += b.z; q.w += b.w;
    }
    atomicAdd(&sums[t * 4 + 0], s.x);
    atomicAdd(&sums[t * 4 + 1], s.y);
    atomicAdd(&sums[t * 4 + 2], s.z);
    atomicAdd(&sums[t * 4 + 3], s.w);
    atomicAdd(&sums[C + t * 4 + 0], q.x);
    atomicAdd(&sums[C + t * 4 + 1], q.y);
    atomicAdd(&sums[C + t * 4 + 2], q.z);
    atomicAdd(&sums[C + t * 4 + 3], q.w);
  }
}

// ---------------- fold BN into per-channel scale/shift ------------------------
__global__ void k_finalize(const float* __restrict__ sums,
                           const float* __restrict__ gamma,
                           const float* __restrict__ beta,
                           float* __restrict__ scale, float* __restrict__ shift,
                           int n) {
  int c = threadIdx.x;
  if (c < C) {
    float inv_n = 1.0f / (float)n;
    float mean = sums[c] * inv_n;
    float var = sums[C + c] * inv_n - mean * mean;
    float rstd = rsqrtf(var + EPS_BN);
    float sc = gamma[c] * rstd;
    scale[c] = sc;
    shift[c] = beta[c] - mean * sc;
  }
}

// ---------------- pass 1: per-block bucket histogram --------------------------
__global__ void k_hist(const int* __restrict__ col, int* __restrict__ histG,
                       int E, int NB, int chunk) {
  __shared__ int h[800];
  int b = blockIdx.x, t = threadIdx.x;
  for (int i = t; i < NB; i += 256) h[i] = 0;
  __syncthreads();
  int s = b * chunk, eend = min(E, s + chunk);
  for (int e = s + t; e < eend; e += 256) atomicAdd(&h[col[e] >> 7], 1);
  __syncthreads();
  for (int i = t; i < NB; i += 256) histG[b * NB + i] = h[i];
}

// ---------------- pass 2a: per-bucket scan over NBLK block counts -------------
__global__ void k_scanH(int* __restrict__ histG, int* __restrict__ btot, int NB) {
  __shared__ int sh[NBLK];
  int q = blockIdx.x, t = threadIdx.x;
  int v = histG[t * NB + q];
  sh[t] = v;
  __syncthreads();
  for (int off = 1; off < NBLK; off <<= 1) {
    int a = (t >= off) ? sh[t - off] : 0;
    __syncthreads();
    sh[t] += a;
    __syncthreads();
  }
  histG[t * NB + q] = sh[t] - v;  // exclusive within bucket
  if (t == NBLK - 1) btot[q] = sh[t];
}

// ---------------- pass 2b: scan bucket totals -> boffs ------------------------
__global__ void k_scanB(const int* __restrict__ btot, int* __restrict__ boffs,
                        int NB, int E) {
  __shared__ int sh[1024];
  int t = threadIdx.x;
  int v = (t < NB) ? btot[t] : 0;
  sh[t] = v;
  __syncthreads();
  for (int off = 1; off < 1024; off <<= 1) {
    int a = (t >= off) ? sh[t - off] : 0;
    __syncthreads();
    sh[t] += a;
    __syncthreads();
  }
  if (t < NB) boffs[t] = sh[t] - v;
  if (t == 0) boffs[NB] = E;
}

// ---------------- pass 3: scatter into disjoint per-(block,bucket) runs ------
__global__ void k_part(const int* __restrict__ row, const int* __restrict__ col,
                       const int* __restrict__ histG, const int* __restrict__ boffs,
                       unsigned* __restrict__ binned, int E, int NB, int chunk) {
  __shared__ int cur[800];
  int b = blockIdx.x, t = threadIdx.x;
  for (int i = t; i < NB; i += 256) cur[i] = boffs[i] + histG[b * NB + i];
  __syncthreads();
  int s = b * chunk, eend = min(E, s + chunk);
  for (int e = s + t; e < eend; e += 256) {
    int c = col[e];
    int pos = atomicAdd(&cur[c >> 7], 1);
    binned[pos] = ((unsigned)(c & 127) << 17) | (unsigned)row[e];
  }
}

// ---------------- reorderC: sort bucket by (src_chunk, dst_local) in place ----
// emits noffs2[b*2048 + chunk*128 + local] segment starts + dis
__global__ __launch_bounds__(256) void k_reorderC(
    unsigned* __restrict__ binned, const int* __restrict__ boffs,
    int* __restrict__ noffs2, float* __restrict__ dis, int n, int E, int NB) {
  __shared__ int cnt[2048];
  __shared__ int cur[2048];
  __shared__ int tsum[256];
  __shared__ int deg[128];
  __shared__ unsigned list[CAP];
  int b = blockIdx.x, t = threadIdx.x;
  for (int i = t; i < 2048; i += 256) cnt[i] = 0;
  __syncthreads();
  int s = boffs[b], e = boffs[b + 1];
  // pass 1: count (chunk-major key = (src>>13)*128 + local)
  for (int i = s + t; i < e; i += 256) {
    unsigned v = binned[i];
    int key = (int)((v & 0x1FFFFu) >> 13) * 128 + (int)(v >> 17);
    atomicAdd(&cnt[key], 1);
  }
  __syncthreads();
  // degree per local node (before cnt is overwritten)
  if (t < 128) {
    int d = 0;
#pragma unroll
    for (int c = 0; c < CHK; ++c) d += cnt[c * 128 + t];
    deg[t] = d;
  }
  __syncthreads();
  // exclusive scan of 2048 counts: 8 serial per thread + H-S over totals
  int b8 = t * 8;
  int tot = 0;
#pragma unroll
  for (int j = 0; j < 8; ++j) tot += cnt[b8 + j];
  tsum[t] = tot;
  __syncthreads();
  for (int off = 1; off < 256; off <<= 1) {
    int a = (t >= off) ? tsum[t - off] : 0;
    __syncthreads();
    tsum[t] += a;
    __syncthreads();
  }
  int run = tsum[t] - tot;
#pragma unroll
  for (int j = 0; j < 8; ++j) {
    int c0 = cnt[b8 + j];
    cnt[b8 + j] = run;   // becomes start offset
    cur[b8 + j] = run;
    run += c0;
  }
  __syncthreads();
  // pass 2: fill sorted list
  for (int i = s + t; i < e; i += 256) {
    unsigned v = binned[i];
    int key = (int)((v & 0x1FFFFu) >> 13) * 128 + (int)(v >> 17);
    int pos = atomicAdd(&cur[key], 1);
    if (pos < CAP) list[pos] = v & 0x1FFFFu;
  }
  __syncthreads();
  // write back in place + emit noffs2 + dis
  int len = e - s;
  for (int i = t; i < len; i += 256) binned[s + i] = list[i];
  for (int k = t; k < 2048; k += 256) noffs2[b * 2048 + k] = s + cnt[k];
  int node = b * 128 + t;
  if (t < 128 && node < n) dis[node] = rsqrtf((float)(deg[t] + 1));
  if (b == NB - 1 && t == 0) noffs2[NB * 2048] = E;
}

// ---------------- old reorder (fallback path): node-sort + noffs --------------
__global__ __launch_bounds__(256) void k_reorderO(
    unsigned* __restrict__ binned, const int* __restrict__ boffs,
    int* __restrict__ noffs, float* __restrict__ dis, int n, int E) {
  __shared__ int cnt[128];
  __shared__ int offs[128];
  __shared__ int cur[128];
  __shared__ int scn[128];
  __shared__ unsigned list[CAP];
  int b = blockIdx.x, t = threadIdx.x;
  if (t < 128) cnt[t] = 0;
  __syncthreads();
  int s = boffs[b], e = boffs[b + 1];
  for (int i = s + t; i < e; i += 256) atomicAdd(&cnt[binned[i] >> 17], 1);
  __syncthreads();
  if (t < 128) scn[t] = cnt[t];
  __syncthreads();
  for (int off = 1; off < 128; off <<= 1) {
    int a = (t >= off && t < 128) ? scn[t - off] : 0;
    __syncthreads();
    if (t < 128) scn[t] += a;
    __syncthreads();
  }
  if (t < 128) {
    offs[t] = scn[t] - cnt[t];
    cur[t] = scn[t] - cnt[t];
  }
  __syncthreads();
  for (int i = s + t; i < e; i += 256) {
    unsigned v = binned[i];
    int pos = atomicAdd(&cur[v >> 17], 1);
    if (pos < CAP) list[pos] = v & 0x1FFFFu;
  }
  __syncthreads();
  int len = e - s;
  for (int i = t; i < len; i += 256) binned[s + i] = list[i];
  int node = b * 128 + t;
  if (t < 128 && node < n) {
    noffs[node] = s + offs[t];
    dis[node] = rsqrtf((float)(cnt[t] + 1));
  }
  if (b == 0 && t == 0) noffs[n] = E;
}

// ---------------- prep: y[r] = bf16x2( (x[r]*scale+shift) * dis[r] ) ----------
__global__ void k_prep(const float2* __restrict__ x2, const float* __restrict__ dis,
                       const float2* __restrict__ scale2,
                       const float2* __restrict__ shift2,
                       unsigned* __restrict__ y, int n) {
  int idx = blockIdx.x * blockDim.x + threadIdx.x;
  int r = idx >> 6;
  if (r >= n) return;
  int lane = idx & 63;
  float d = dis[r];
  float2 v = x2[(size_t)r * 64 + lane];
  float2 sc = scale2[lane], sh = shift2[lane];
  float y0 = (v.x * sc.x + sh.x) * d;
  float y1 = (v.y * sc.y + sh.y) * d;
  y[(size_t)r * 64 + lane] = (bf16_rne(y1) << 16) | bf16_rne(y0);
}

// ---------------- G2: chunk-phased gather + self-loop, split-bf16 out ---------
// g[v] = dis[v] * ( sum_e y[r_e] + y[v] ); edges walked chunk-by-chunk for L2
__global__ __launch_bounds__(256) void k_G2(
    const unsigned* __restrict__ y, const unsigned* __restrict__ lst,
    const int* __restrict__ noffs2, const float* __restrict__ dis,
    unsigned* __restrict__ ghi, unsigned* __restrict__ glo, int n) {
  int w = (blockIdx.x * blockDim.x + threadIdx.x) >> 6;
  if (w >= n) return;
  int lane = threadIdx.x & 63;
  int nb2 = (w >> 7) * 2048 + (w & 127);
  float2 a0 = make_float2(0.f, 0.f), a1 = make_float2(0.f, 0.f);
  float2 a2 = make_float2(0.f, 0.f), a3 = make_float2(0.f, 0.f);
#pragma unroll 1
  for (int c = 0; c < CHK; ++c) {
    int si = noffs2[nb2 + c * 128];
    int ei = noffs2[nb2 + c * 128 + 1];
    int i = si;
    for (; i + 3 < ei; i += 4) {
      int r0 = lst[i], r1 = lst[i + 1], r2 = lst[i + 2], r3 = lst[i + 3];
      unsigned u0 = y[(size_t)r0 * 64 + lane];
      unsigned u1 = y[(size_t)r1 * 64 + lane];
      unsigned u2 = y[(size_t)r2 * 64 + lane];
      unsigned u3 = y[(size_t)r3 * 64 + lane];
      a0.x += __uint_as_float(u0 << 16); a0.y += __uint_as_float(u0 & 0xFFFF0000u);
      a1.x += __uint_as_float(u1 << 16); a1.y += __uint_as_float(u1 & 0xFFFF0000u);
      a2.x += __uint_as_float(u2 << 16); a2.y += __uint_as_float(u2 & 0xFFFF0000u);
      a3.x += __uint_as_float(u3 << 16); a3.y += __uint_as_float(u3 & 0xFFFF0000u);
    }
    if (i + 1 < ei) {
      int r0 = lst[i], r1 = lst[i + 1];
      unsigned u0 = y[(size_t)r0 * 64 + lane];
      unsigned u1 = y[(size_t)r1 * 64 + lane];
      a0.x += __uint_as_float(u0 << 16); a0.y += __uint_as_float(u0 & 0xFFFF0000u);
      a1.x += __uint_as_float(u1 << 16); a1.y += __uint_as_float(u1 & 0xFFFF0000u);
      i += 2;
    }
    if (i < ei) {
      unsigned u = y[(size_t)lst[i] * 64 + lane];
      a0.x += __uint_as_float(u << 16); a0.y += __uint_as_float(u & 0xFFFF0000u);
    }
  }
  {  // self loop
    unsigned u = y[(size_t)w * 64 + lane];
    a0.x += __uint_as_float(u << 16); a0.y += __uint_as_float(u & 0xFFFF0000u);
  }
  float dc = dis[w];
  float gx = dc * (a0.x + a1.x + a2.x + a3.x);
  float gy = dc * (a0.y + a1.y + a2.y + a3.y);
  unsigned hx = bf16_rne(gx), hy = bf16_rne(gy);
  unsigned lx = bf16_rne(gx - bf16_f(hx)), ly = bf16_rne(gy - bf16_f(hy));
  size_t o = (size_t)w * 64 + lane;
  ghi[o] = (hy << 16) | hx;
  glo[o] = (ly << 16) | lx;
}

// ---------------- MFMA GEMM (R9-proven): out = relu((ghi+glo) @ W + b) --------
__global__ __launch_bounds__(256) void k_gemmM(
    const unsigned* __restrict__ ghi, const unsigned* __restrict__ glo,
    const float* __restrict__ W, const float* __restrict__ bias,
    float* __restrict__ out, int n) {
  __shared__ __align__(16) unsigned short sGh[64][136];
  __shared__ __align__(16) unsigned short sGl[64][136];
  __shared__ __align__(16) unsigned short sWt[128][136];
  int t = threadIdx.x;
  int rowBase = blockIdx.x * 64;
  for (int i = t; i < 16384; i += 256) {
    int k = i >> 7, c = i & 127;
    sWt[c][k] = (unsigned short)bf16_rne(W[i]);
  }
  for (int i = t; i < 4096; i += 256) {
    int r = i >> 6, c = i & 63;
    int rw = rowBase + r;
    unsigned uh = 0, ul = 0;
    if (rw < n) {
      uh = ghi[(size_t)rw * 64 + c];
      ul = glo[(size_t)rw * 64 + c];
    }
    *(unsigned*)&sGh[r][c * 2] = uh;
    *(unsigned*)&sGl[r][c * 2] = ul;
  }
  __syncthreads();
  int w = t >> 6, l = t & 63;
  int m16 = l & 15, kb = l >> 4;
  int rtile = w * 16;
  f32x4 acc[8];
#pragma unroll
  for (int i = 0; i < 8; ++i) acc[i] = (f32x4){0.f, 0.f, 0.f, 0.f};
#pragma unroll
  for (int kt = 0; kt < 4; ++kt) {
    int koff = kt * 32 + kb * 8;
    bf16x8 ah = *(const bf16x8*)&sGh[rtile + m16][koff];
    bf16x8 al = *(const bf16x8*)&sGl[rtile + m16][koff];
#pragma unroll
    for (int nt = 0; nt < 8; ++nt) {
      bf16x8 bb = *(const bf16x8*)&sWt[nt * 16 + m16][koff];
      acc[nt] = __builtin_amdgcn_mfma_f32_16x16x32_bf16(ah, bb, acc[nt], 0, 0, 0);
      acc[nt] = __builtin_amdgcn_mfma_f32_16x16x32_bf16(al, bb, acc[nt], 0, 0, 0);
    }
  }
#pragma unroll
  for (int nt = 0; nt < 8; ++nt) {
    int colc = nt * 16 + m16;
    float bv = bias[colc];
#pragma unroll
    for (int reg = 0; reg < 4; ++reg) {
      int row = rowBase + rtile + kb * 4 + reg;
      if (row < n) {
        float o = acc[nt][reg] + bv;
        out[(size_t)row * C + colc] = fmaxf(o, 0.f);
      }
    }
  }
}

// ---------------- old gather (fallback): writes fp32 out ----------------------
__global__ __launch_bounds__(256) void k_G(
    const unsigned* __restrict__ y, const unsigned* __restrict__ lst,
    const int* __restrict__ noffs, const float* __restrict__ dis,
    const float2* __restrict__ x2, const float2* __restrict__ scale2,
    const float2* __restrict__ shift2, float2* __restrict__ out2,
    int n, int useY) {
  int w = (blockIdx.x * blockDim.x + threadIdx.x) >> 6;
  if (w >= n) return;
  int lane = threadIdx.x & 63;
  int s = noffs[w], t = noffs[w + 1];
  float2 a0 = make_float2(0.f, 0.f), a1 = make_float2(0.f, 0.f);
  float2 a2 = make_float2(0.f, 0.f), a3 = make_float2(0.f, 0.f);
  if (useY) {
    int i = s;
    for (; i + 3 < t; i += 4) {
      int r0 = lst[i], r1 = lst[i + 1], r2 = lst[i + 2], r3 = lst[i + 3];
      unsigned u0 = y[(size_t)r0 * 64 + lane];
      unsigned u1 = y[(size_t)r1 * 64 + lane];
      unsigned u2 = y[(size_t)r2 * 64 + lane];
      unsigned u3 = y[(size_t)r3 * 64 + lane];
      a0.x += __uint_as_float(u0 << 16); a0.y += __uint_as_float(u0 & 0xFFFF0000u);
      a1.x += __uint_as_float(u1 << 16); a1.y += __uint_as_float(u1 & 0xFFFF0000u);
      a2.x += __uint_as_float(u2 << 16); a2.y += __uint_as_float(u2 & 0xFFFF0000u);
      a3.x += __uint_as_float(u3 << 16); a3.y += __uint_as_float(u3 & 0xFFFF0000u);
    }
    for (; i < t; ++i) {
      unsigned u = y[(size_t)lst[i] * 64 + lane];
      a0.x += __uint_as_float(u << 16); a0.y += __uint_as_float(u & 0xFFFF0000u);
    }
    float dc = dis[w];
    float2 o;
    o.x = dc * (a0.x + a1.x + a2.x + a3.x);
    o.y = dc * (a0.y + a1.y + a2.y + a3.y);
    out2[(size_t)w * 64 + lane] = o;
  } else {
    float sd = 0.f;
    for (int i = s; i < t; ++i) {
      int r = lst[i];
      float d = dis[r];
      float2 v = x2[(size_t)r * 64 + lane];
      a0.x += v.x * d; a0.y += v.y * d; sd += d;
    }
    float dc = dis[w];
    float2 sc = scale2[lane], sh = shift2[lane];
    float2 o;
    o.x = dc * (a0.x * sc.x + sd * sh.x);
    o.y = dc * (a0.y * sc.y + sd * sh.y);
    out2[(size_t)w * 64 + lane] = o;
  }
}

// ---------------- old scalar GEMM (fallback) ----------------------------------
__global__ __launch_bounds__(256) void k_gemm(float* __restrict__ out,
                        const float4* __restrict__ x4,
                        const float* __restrict__ W,
                        const float* __restrict__ bias,
                        const float* __restrict__ scale,
                        const float* __restrict__ shift,
                        const float* __restrict__ dis, int n) {
  __shared__ float sW[64 * C];
  __shared__ float sG[32 * C];
  int t = threadIdx.x;
  int rowBase = blockIdx.x * 32;

  const float4* scale4 = (const float4*)scale;
  const float4* shift4 = (const float4*)shift;
  float4* sG4 = (float4*)sG;
  float4* sW4 = (float4*)sW;
  const float4* W4 = (const float4*)W;
  const float4* out4 = (const float4*)out;

  for (int i = t; i < 32 * CG; i += 256) {
    int r = i >> 5, g = i & 31;
    int rw = rowBase + r;
    float4 acc = make_float4(0.f, 0.f, 0.f, 0.f);
    if (rw < n) {
      acc = out4[(size_t)rw * CG + g];
      float4 xv = x4[(size_t)rw * CG + g];
      float d = dis[rw];
      float inv = d * d;
      float4 sc = scale4[g];
      float4 sh = shift4[g];
      acc.x += (xv.x * sc.x + sh.x) * inv;
      acc.y += (xv.y * sc.y + sh.y) * inv;
      acc.z += (xv.z * sc.z + sh.z) * inv;
      acc.w += (xv.w * sc.w + sh.w) * inv;
    }
    sG4[i] = acc;
  }

  int tx = t & 127;
  int ty = t >> 7;
  float acc[16];
#pragma unroll
  for (int i = 0; i < 16; ++i) acc[i] = 0.f;

  for (int kc = 0; kc < 2; ++kc) {
    for (int i = t; i < 64 * C / 4; i += 256) sW4[i] = W4[kc * 2048 + i];
    __syncthreads();
#pragma unroll 4
    for (int k = 0; k < 64; ++k) {
      float w = sW[k * C + tx];
#pragma unroll
      for (int rr = 0; rr < 16; ++rr)
        acc[rr] += sG[(rr * 2 + ty) * C + kc * 64 + k] * w;
    }
    __syncthreads();
  }

  float bv = bias[tx];
#pragma unroll
  for (int rr = 0; rr < 16; ++rr) {
    int rw = rowBase + rr * 2 + ty;
    if (rw < n) {
      float o = acc[rr] + bv;
      out[(size_t)rw * C + tx] = o > 0.f ? o : 0.f;
    }
  }
}

extern "C" void kernel_launch(void* const* d_in, const int* in_sizes, int n_in,
                              void* d_out, int out_size, void* d_ws, size_t ws_size,
                              hipStream_t stream) {
  const float* x = (const float*)d_in[0];
  const int* edge = (const int*)d_in[1];
  const float* gamma = (const float*)d_in[2];
  const float* beta = (const float*)d_in[3];
  const float* W = (const float*)d_in[4];
  const float* bias = (const float*)d_in[5];
  float* out = (float*)d_out;

  int n = in_sizes[0] / C;
  int E = in_sizes[1] / 2;
  int NB = (n + 127) / 128;           // buckets of 128 dst nodes (<=800)
  int chunk = (E + NBLK - 1) / NBLK;  // edges per partition block

  float* ws = (float*)d_ws;
  float* sums = ws;                      // 256 f
  float* scale = ws + 256;               // 128 f
  float* shift = ws + 384;               // 128 f
  float* dis = ws + 512;                 // n f
  int* btot = (int*)(ws + 512 + n);      // NB i
  int* boffs = btot + NB;                // NB+1 i
  int* noffs = boffs + NB + 1;           // n+1 i (fallback path)
  int* histG = noffs + n + 1;            // NBLK*NB i
  unsigned* binned = (unsigned*)(histG + (size_t)NBLK * NB);  // E u32
  unsigned* y = binned + E;              // n*64 u32 (bf16x2 rows)
  unsigned* ghi = y + (size_t)n * 64;    // n*64 u32
  unsigned* glo = ghi + (size_t)n * 64;  // n*64 u32
  int* noffs2 = (int*)(glo + (size_t)n * 64);  // NB*2048+1 i

  size_t base = (size_t)512 + n + NB + (NB + 1) + (n + 1) +
                (size_t)NBLK * NB + E;
  size_t need_old = base + (size_t)n * 64;
  size_t need_new = base + (size_t)n * 64 * 3 + (size_t)NB * 2048 + 1;
  int mode = (ws_size >= need_new * 4) ? 2 : (ws_size >= need_old * 4) ? 1 : 0;

  k_init<<<1, 256, 0, stream>>>(sums);
  k_stats<<<256, 256, 0, stream>>>((const float4*)x, sums, n);
  k_finalize<<<1, 128, 0, stream>>>(sums, gamma, beta, scale, shift, n);
  k_hist<<<NBLK, 256, 0, stream>>>(edge + E, histG, E, NB, chunk);
  k_scanH<<<NB, NBLK, 0, stream>>>(histG, btot, NB);
  k_scanB<<<1, 1024, 0, stream>>>(btot, boffs, NB, E);
  k_part<<<NBLK, 256, 0, stream>>>(edge, edge + E, histG, boffs, binned, E, NB, chunk);
  if (mode == 2) {
    k_reorderC<<<NB, 256, 0, stream>>>(binned, boffs, noffs2, dis, n, E, NB);
    k_prep<<<(n * 64 + 255) / 256, 256, 0, stream>>>(
        (const float2*)x, dis, (const float2*)scale, (const float2*)shift, y, n);
    k_G2<<<(n * 64 + 255) / 256, 256, 0, stream>>>(y, binned, noffs2, dis,
                                                   ghi, glo, n);
    k_gemmM<<<(n + 63) / 64, 256, 0, stream>>>(ghi, glo, W, bias, out, n);
  } else {
    k_reorderO<<<NB, 256, 0, stream>>>(binned, boffs, noffs, dis, n, E);
    if (mode >= 1) {
      k_prep<<<(n * 64 + 255) / 256, 256, 0, stream>>>(
          (const float2*)x, dis, (const float2*)scale, (const float2*)shift, y, n);
    }
    k_G<<<(n * 64 + 255) / 256, 256, 0, stream>>>(
        y, binned, noffs, dis, (const float2*)x, (const float2*)scale,
        (const float2*)shift, (float2*)out, n, mode);
    k_gemm<<<(n + 31) / 32, 256, 0, stream>>>(out, (const float4*)x, W, bias,
                                              scale, shift, dis, n);
  }
}

// Round 12
// 345.891 us; speedup vs baseline: 1.2786x; 1.2786x over previous
//
#include <hip/hip_runtime.h>

#define EPS_BN 1e-5f
#define C 128
#define CG 32     // float4 groups per 128-channel row
#define CAP 6144  // per-bucket edge capacity in LDS (mean 4096, sigma ~64)
#define NBLK 256  // partition blocks

typedef __attribute__((ext_vector_type(8))) short bf16x8;
typedef __attribute__((ext_vector_type(4))) float f32x4;

__device__ inline unsigned bf16_rne(float f) {
  unsigned u = __float_as_uint(f);
  return (u + 0x7FFFu + ((u >> 16) & 1u)) >> 16;
}
__device__ inline float bf16_f(unsigned h) { return __uint_as_float(h << 16); }

// ---------------- init: zero BN accumulators ----------------------------------
__global__ void k_init(float* __restrict__ sums) {
  int i = blockIdx.x * blockDim.x + threadIdx.x;
  if (i < 256) sums[i] = 0.0f;
}

// ---------------- column sum / sumsq over rows --------------------------------
__global__ void k_stats(const float4* __restrict__ x4, float* __restrict__ sums, int n) {
  __shared__ float4 s_s[256];
  __shared__ float4 s_q[256];
  int t = threadIdx.x;
  int cg = t & 31;
  int rl = t >> 5;
  float4 s = make_float4(0.f, 0.f, 0.f, 0.f);
  float4 q = make_float4(0.f, 0.f, 0.f, 0.f);
  for (int r = blockIdx.x * 8 + rl; r < n; r += gridDim.x * 8) {
    float4 v = x4[(size_t)r * CG + cg];
    s.x += v.x; s.y += v.y; s.z += v.z; s.w += v.w;
    q.x += v.x * v.x; q.y += v.y * v.y; q.z += v.z * v.z; q.w += v.w * v.w;
  }
  s_s[t] = s; s_q[t] = q;
  __syncthreads();
  if (t < 32) {
    for (int j = 1; j < 8; ++j) {
      float4 a = s_s[t + 32 * j];
      float4 b = s_q[t + 32 * j];
      s.x += a.x; s.y += a.y; s.z += a.z; s.w += a.w;
      q.x += b.x; q.y += b.y; q.z += b.z; q.w += b.w;
    }
    atomicAdd(&sums[t * 4 + 0], s.x);
    atomicAdd(&sums[t * 4 + 1], s.y);
    atomicAdd(&sums[t * 4 + 2], s.z);
    atomicAdd(&sums[t * 4 + 3], s.w);
    atomicAdd(&sums[C + t * 4 + 0], q.x);
    atomicAdd(&sums[C + t * 4 + 1], q.y);
    atomicAdd(&sums[C + t * 4 + 2], q.z);
    atomicAdd(&sums[C + t * 4 + 3], q.w);
  }
}

// ---------------- fold BN into per-channel scale/shift ------------------------
__global__ void k_finalize(const float* __restrict__ sums,
                           const float* __restrict__ gamma,
                           const float* __restrict__ beta,
                           float* __restrict__ scale, float* __restrict__ shift,
                           int n) {
  int c = threadIdx.x;
  if (c < C) {
    float inv_n = 1.0f / (float)n;
    float mean = sums[c] * inv_n;
    float var = sums[C + c] * inv_n - mean * mean;
    float rstd = rsqrtf(var + EPS_BN);
    float sc = gamma[c] * rstd;
    scale[c] = sc;
    shift[c] = beta[c] - mean * sc;
  }
}

// ---------------- pass 1: per-block bucket histogram --------------------------
__global__ void k_hist(const int* __restrict__ col, int* __restrict__ histG,
                       int E, int NB, int chunk) {
  __shared__ int h[800];
  int b = blockIdx.x, t = threadIdx.x;
  for (int i = t; i < NB; i += 256) h[i] = 0;
  __syncthreads();
  int s = b * chunk, eend = min(E, s + chunk);
  for (int e = s + t; e < eend; e += 256) atomicAdd(&h[col[e] >> 7], 1);
  __syncthreads();
  for (int i = t; i < NB; i += 256) histG[b * NB + i] = h[i];
}

// ---------------- pass 2a: per-bucket scan over NBLK block counts -------------
__global__ void k_scanH(int* __restrict__ histG, int* __restrict__ btot, int NB) {
  __shared__ int sh[NBLK];
  int q = blockIdx.x, t = threadIdx.x;
  int v = histG[t * NB + q];
  sh[t] = v;
  __syncthreads();
  for (int off = 1; off < NBLK; off <<= 1) {
    int a = (t >= off) ? sh[t - off] : 0;
    __syncthreads();
    sh[t] += a;
    __syncthreads();
  }
  histG[t * NB + q] = sh[t] - v;  // exclusive within bucket
  if (t == NBLK - 1) btot[q] = sh[t];
}

// ---------------- pass 2b: scan bucket totals -> boffs ------------------------
__global__ void k_scanB(const int* __restrict__ btot, int* __restrict__ boffs,
                        int NB, int E) {
  __shared__ int sh[1024];
  int t = threadIdx.x;
  int v = (t < NB) ? btot[t] : 0;
  sh[t] = v;
  __syncthreads();
  for (int off = 1; off < 1024; off <<= 1) {
    int a = (t >= off) ? sh[t - off] : 0;
    __syncthreads();
    sh[t] += a;
    __syncthreads();
  }
  if (t < NB) boffs[t] = sh[t] - v;
  if (t == 0) boffs[NB] = E;
}

// ---------------- pass 3: scatter into disjoint per-(block,bucket) runs ------
__global__ void k_part(const int* __restrict__ row, const int* __restrict__ col,
                       const int* __restrict__ histG, const int* __restrict__ boffs,
                       unsigned* __restrict__ binned, int E, int NB, int chunk) {
  __shared__ int cur[800];
  int b = blockIdx.x, t = threadIdx.x;
  for (int i = t; i < NB; i += 256) cur[i] = boffs[i] + histG[b * NB + i];
  __syncthreads();
  int s = b * chunk, eend = min(E, s + chunk);
  for (int e = s + t; e < eend; e += 256) {
    int c = col[e];
    int pos = atomicAdd(&cur[c >> 7], 1);
    binned[pos] = ((unsigned)(c & 127) << 17) | (unsigned)row[e];
  }
}

// ---------------- reorder: node-sort bucket in place; emit noffs + dis --------
__global__ __launch_bounds__(256) void k_reorder(
    unsigned* __restrict__ binned, const int* __restrict__ boffs,
    int* __restrict__ noffs, float* __restrict__ dis, int n, int E) {
  __shared__ int cnt[128];
  __shared__ int offs[128];
  __shared__ int cur[128];
  __shared__ int scn[128];
  __shared__ unsigned list[CAP];
  int b = blockIdx.x, t = threadIdx.x;
  if (t < 128) cnt[t] = 0;
  __syncthreads();
  int s = boffs[b], e = boffs[b + 1];
  for (int i = s + t; i < e; i += 256) atomicAdd(&cnt[binned[i] >> 17], 1);
  __syncthreads();
  if (t < 128) scn[t] = cnt[t];
  __syncthreads();
  for (int off = 1; off < 128; off <<= 1) {
    int a = (t >= off && t < 128) ? scn[t - off] : 0;
    __syncthreads();
    if (t < 128) scn[t] += a;
    __syncthreads();
  }
  if (t < 128) {
    offs[t] = scn[t] - cnt[t];
    cur[t] = scn[t] - cnt[t];
  }
  __syncthreads();
  for (int i = s + t; i < e; i += 256) {
    unsigned v = binned[i];
    int pos = atomicAdd(&cur[v >> 17], 1);
    if (pos < CAP) list[pos] = v & 0x1FFFFu;
  }
  __syncthreads();
  int len = e - s;
  for (int i = t; i < len; i += 256) binned[s + i] = list[i];
  int node = b * 128 + t;
  if (t < 128 && node < n) {
    noffs[node] = s + offs[t];
    dis[node] = rsqrtf((float)(cnt[t] + 1));
  }
  if (b == 0 && t == 0) noffs[n] = E;
}

// ---------------- prep: y[r] = bf16x2( (x[r]*scale+shift) * dis[r] ) ----------
__global__ void k_prep(const float2* __restrict__ x2, const float* __restrict__ dis,
                       const float2* __restrict__ scale2,
                       const float2* __restrict__ shift2,
                       unsigned* __restrict__ y, int n) {
  int idx = blockIdx.x * blockDim.x + threadIdx.x;
  int r = idx >> 6;
  if (r >= n) return;
  int lane = idx & 63;
  float d = dis[r];
  float2 v = x2[(size_t)r * 64 + lane];
  float2 sc = scale2[lane], sh = shift2[lane];
  float y0 = (v.x * sc.x + sh.x) * d;
  float y1 = (v.y * sc.y + sh.y) * d;
  y[(size_t)r * 64 + lane] = (bf16_rne(y1) << 16) | bf16_rne(y0);
}

// ---------------- G2: half-wave-pair gather + self-loop, split-bf16 out -------
// g[v] = dis[v] * ( sum_e y[r_e] + y[v] )
// lanes 0-31 / 32-63 process even/odd edges; each lane owns 4 channels.
__global__ __launch_bounds__(256) void k_G2(
    const unsigned* __restrict__ y, const unsigned* __restrict__ lst,
    const int* __restrict__ noffs, const float* __restrict__ dis,
    unsigned* __restrict__ ghi, unsigned* __restrict__ glo, int n) {
  int w = (blockIdx.x * blockDim.x + threadIdx.x) >> 6;
  if (w >= n) return;
  int lane = threadIdx.x & 63;
  int h = lane >> 5;   // half
  int q = lane & 31;   // channel quad: channels 4q..4q+3
  int s = noffs[w], t = noffs[w + 1];
  float4 a0 = make_float4(0.f, 0.f, 0.f, 0.f);
  float4 a1 = make_float4(0.f, 0.f, 0.f, 0.f);
  float4 a2 = make_float4(0.f, 0.f, 0.f, 0.f);
  float4 a3 = make_float4(0.f, 0.f, 0.f, 0.f);
  int i = s;
  for (; i + 7 < t; i += 8) {
    int r0 = lst[i + h],     r1 = lst[i + 2 + h];
    int r2 = lst[i + 4 + h], r3 = lst[i + 6 + h];
    uint2 u0 = *(const uint2*)(y + (size_t)r0 * 64 + q * 2);
    uint2 u1 = *(const uint2*)(y + (size_t)r1 * 64 + q * 2);
    uint2 u2 = *(const uint2*)(y + (size_t)r2 * 64 + q * 2);
    uint2 u3 = *(const uint2*)(y + (size_t)r3 * 64 + q * 2);
    a0.x += __uint_as_float(u0.x << 16); a0.y += __uint_as_float(u0.x & 0xFFFF0000u);
    a0.z += __uint_as_float(u0.y << 16); a0.w += __uint_as_float(u0.y & 0xFFFF0000u);
    a1.x += __uint_as_float(u1.x << 16); a1.y += __uint_as_float(u1.x & 0xFFFF0000u);
    a1.z += __uint_as_float(u1.y << 16); a1.w += __uint_as_float(u1.y & 0xFFFF0000u);
    a2.x += __uint_as_float(u2.x << 16); a2.y += __uint_as_float(u2.x & 0xFFFF0000u);
    a2.z += __uint_as_float(u2.y << 16); a2.w += __uint_as_float(u2.y & 0xFFFF0000u);
    a3.x += __uint_as_float(u3.x << 16); a3.y += __uint_as_float(u3.x & 0xFFFF0000u);
    a3.z += __uint_as_float(u3.y << 16); a3.w += __uint_as_float(u3.y & 0xFFFF0000u);
  }
  for (int j = i + h; j < t; j += 2) {
    uint2 u = *(const uint2*)(y + (size_t)lst[j] * 64 + q * 2);
    a0.x += __uint_as_float(u.x << 16); a0.y += __uint_as_float(u.x & 0xFFFF0000u);
    a0.z += __uint_as_float(u.y << 16); a0.w += __uint_as_float(u.y & 0xFFFF0000u);
  }
  if (h == 0) {  // self loop, added exactly once
    uint2 u = *(const uint2*)(y + (size_t)w * 64 + q * 2);
    a0.x += __uint_as_float(u.x << 16); a0.y += __uint_as_float(u.x & 0xFFFF0000u);
    a0.z += __uint_as_float(u.y << 16); a0.w += __uint_as_float(u.y & 0xFFFF0000u);
  }
  float vx = a0.x + a1.x + a2.x + a3.x;
  float vy = a0.y + a1.y + a2.y + a3.y;
  float vz = a0.z + a1.z + a2.z + a3.z;
  float vw = a0.w + a1.w + a2.w + a3.w;
  vx += __shfl_xor(vx, 32);
  vy += __shfl_xor(vy, 32);
  vz += __shfl_xor(vz, 32);
  vw += __shfl_xor(vw, 32);
  if (h == 0) {
    float dc = dis[w];
    float g0 = dc * vx, g1 = dc * vy, g2 = dc * vz, g3 = dc * vw;
    unsigned h0 = bf16_rne(g0), h1 = bf16_rne(g1);
    unsigned h2 = bf16_rne(g2), h3 = bf16_rne(g3);
    unsigned l0 = bf16_rne(g0 - bf16_f(h0)), l1 = bf16_rne(g1 - bf16_f(h1));
    unsigned l2 = bf16_rne(g2 - bf16_f(h2)), l3 = bf16_rne(g3 - bf16_f(h3));
    uint2 hw, lw;
    hw.x = (h1 << 16) | h0; hw.y = (h3 << 16) | h2;
    lw.x = (l1 << 16) | l0; lw.y = (l3 << 16) | l2;
    *(uint2*)(ghi + (size_t)w * 64 + q * 2) = hw;
    *(uint2*)(glo + (size_t)w * 64 + q * 2) = lw;
  }
}

// ---------------- MFMA GEMM (R7 LDS version): out = relu((ghi+glo)@W + b) -----
__global__ __launch_bounds__(256) void k_gemmM(
    const unsigned* __restrict__ ghi, const unsigned* __restrict__ glo,
    const float* __restrict__ W, const float* __restrict__ bias,
    float* __restrict__ out, int n) {
  __shared__ __align__(16) unsigned short sGh[64][136];
  __shared__ __align__(16) unsigned short sGl[64][136];
  __shared__ __align__(16) unsigned short sWt[128][136];
  int t = threadIdx.x;
  int rowBase = blockIdx.x * 64;
  for (int i = t; i < 16384; i += 256) {
    int k = i >> 7, c = i & 127;
    sWt[c][k] = (unsigned short)bf16_rne(W[i]);
  }
  for (int i = t; i < 4096; i += 256) {
    int r = i >> 6, c = i & 63;
    int rw = rowBase + r;
    unsigned uh = 0, ul = 0;
    if (rw < n) {
      uh = ghi[(size_t)rw * 64 + c];
      ul = glo[(size_t)rw * 64 + c];
    }
    *(unsigned*)&sGh[r][c * 2] = uh;
    *(unsigned*)&sGl[r][c * 2] = ul;
  }
  __syncthreads();
  int w = t >> 6, l = t & 63;
  int m16 = l & 15, kb = l >> 4;
  int rtile = w * 16;
  f32x4 acc[8];
#pragma unroll
  for (int i = 0; i < 8; ++i) acc[i] = (f32x4){0.f, 0.f, 0.f, 0.f};
#pragma unroll
  for (int kt = 0; kt < 4; ++kt) {
    int koff = kt * 32 + kb * 8;
    bf16x8 ah = *(const bf16x8*)&sGh[rtile + m16][koff];
    bf16x8 al = *(const bf16x8*)&sGl[rtile + m16][koff];
#pragma unroll
    for (int nt = 0; nt < 8; ++nt) {
      bf16x8 bb = *(const bf16x8*)&sWt[nt * 16 + m16][koff];
      acc[nt] = __builtin_amdgcn_mfma_f32_16x16x32_bf16(ah, bb, acc[nt], 0, 0, 0);
      acc[nt] = __builtin_amdgcn_mfma_f32_16x16x32_bf16(al, bb, acc[nt], 0, 0, 0);
    }
  }
#pragma unroll
  for (int nt = 0; nt < 8; ++nt) {
    int colc = nt * 16 + m16;
    float bv = bias[colc];
#pragma unroll
    for (int reg = 0; reg < 4; ++reg) {
      int row = rowBase + rtile + kb * 4 + reg;
      if (row < n) {
        float o = acc[nt][reg] + bv;
        out[(size_t)row * C + colc] = fmaxf(o, 0.f);
      }
    }
  }
}

// ---------------- old gather (fallback): writes fp32 out ----------------------
__global__ __launch_bounds__(256) void k_G(
    const unsigned* __restrict__ y, const unsigned* __restrict__ lst,
    const int* __restrict__ noffs, const float* __restrict__ dis,
    const float2* __restrict__ x2, const float2* __restrict__ scale2,
    const float2* __restrict__ shift2, float2* __restrict__ out2,
    int n, int useY) {
  int w = (blockIdx.x * blockDim.x + threadIdx.x) >> 6;
  if (w >= n) return;
  int lane = threadIdx.x & 63;
  int s = noffs[w], t = noffs[w + 1];
  float2 a0 = make_float2(0.f, 0.f), a1 = make_float2(0.f, 0.f);
  float2 a2 = make_float2(0.f, 0.f), a3 = make_float2(0.f, 0.f);
  if (useY) {
    int i = s;
    for (; i + 3 < t; i += 4) {
      int r0 = lst[i], r1 = lst[i + 1], r2 = lst[i + 2], r3 = lst[i + 3];
      unsigned u0 = y[(size_t)r0 * 64 + lane];
      unsigned u1 = y[(size_t)r1 * 64 + lane];
      unsigned u2 = y[(size_t)r2 * 64 + lane];
      unsigned u3 = y[(size_t)r3 * 64 + lane];
      a0.x += __uint_as_float(u0 << 16); a0.y += __uint_as_float(u0 & 0xFFFF0000u);
      a1.x += __uint_as_float(u1 << 16); a1.y += __uint_as_float(u1 & 0xFFFF0000u);
      a2.x += __uint_as_float(u2 << 16); a2.y += __uint_as_float(u2 & 0xFFFF0000u);
      a3.x += __uint_as_float(u3 << 16); a3.y += __uint_as_float(u3 & 0xFFFF0000u);
    }
    for (; i < t; ++i) {
      unsigned u = y[(size_t)lst[i] * 64 + lane];
      a0.x += __uint_as_float(u << 16); a0.y += __uint_as_float(u & 0xFFFF0000u);
    }
    float dc = dis[w];
    float2 o;
    o.x = dc * (a0.x + a1.x + a2.x + a3.x);
    o.y = dc * (a0.y + a1.y + a2.y + a3.y);
    out2[(size_t)w * 64 + lane] = o;
  } else {
    float sd = 0.f;
    for (int i = s; i < t; ++i) {
      int r = lst[i];
      float d = dis[r];
      float2 v = x2[(size_t)r * 64 + lane];
      a0.x += v.x * d; a0.y += v.y * d; sd += d;
    }
    float dc = dis[w];
    float2 sc = scale2[lane], sh = shift2[lane];
    float2 o;
    o.x = dc * (a0.x * sc.x + sd * sh.x);
    o.y = dc * (a0.y * sc.y + sd * sh.y);
    out2[(size_t)w * 64 + lane] = o;
  }
}

// ---------------- old scalar GEMM (fallback) ----------------------------------
__global__ __launch_bounds__(256) void k_gemm(float* __restrict__ out,
                        const float4* __restrict__ x4,
                        const float* __restrict__ W,
                        const float* __restrict__ bias,
                        const float* __restrict__ scale,
                        const float* __restrict__ shift,
                        const float* __restrict__ dis, int n) {
  __shared__ float sW[64 * C];
  __shared__ float sG[32 * C];
  int t = threadIdx.x;
  int rowBase = blockIdx.x * 32;

  const float4* scale4 = (const float4*)scale;
  const float4* shift4 = (const float4*)shift;
  float4* sG4 = (float4*)sG;
  float4* sW4 = (float4*)sW;
  const float4* W4 = (const float4*)W;
  const float4* out4 = (const float4*)out;

  for (int i = t; i < 32 * CG; i += 256) {
    int r = i >> 5, g = i & 31;
    int rw = rowBase + r;
    float4 acc = make_float4(0.f, 0.f, 0.f, 0.f);
    if (rw < n) {
      acc = out4[(size_t)rw * CG + g];
      float4 xv = x4[(size_t)rw * CG + g];
      float d = dis[rw];
      float inv = d * d;
      float4 sc = scale4[g];
      float4 sh = shift4[g];
      acc.x += (xv.x * sc.x + sh.x) * inv;
      acc.y += (xv.y * sc.y + sh.y) * inv;
      acc.z += (xv.z * sc.z + sh.z) * inv;
      acc.w += (xv.w * sc.w + sh.w) * inv;
    }
    sG4[i] = acc;
  }

  int tx = t & 127;
  int ty = t >> 7;
  float acc[16];
#pragma unroll
  for (int i = 0; i < 16; ++i) acc[i] = 0.f;

  for (int kc = 0; kc < 2; ++kc) {
    for (int i = t; i < 64 * C / 4; i += 256) sW4[i] = W4[kc * 2048 + i];
    __syncthreads();
#pragma unroll 4
    for (int k = 0; k < 64; ++k) {
      float w = sW[k * C + tx];
#pragma unroll
      for (int rr = 0; rr < 16; ++rr)
        acc[rr] += sG[(rr * 2 + ty) * C + kc * 64 + k] * w;
    }
    __syncthreads();
  }

  float bv = bias[tx];
#pragma unroll
  for (int rr = 0; rr < 16; ++rr) {
    int rw = rowBase + rr * 2 + ty;
    if (rw < n) {
      float o = acc[rr] + bv;
      out[(size_t)rw * C + tx] = o > 0.f ? o : 0.f;
    }
  }
}

extern "C" void kernel_launch(void* const* d_in, const int* in_sizes, int n_in,
                              void* d_out, int out_size, void* d_ws, size_t ws_size,
                              hipStream_t stream) {
  const float* x = (const float*)d_in[0];
  const int* edge = (const int*)d_in[1];
  const float* gamma = (const float*)d_in[2];
  const float* beta = (const float*)d_in[3];
  const float* W = (const float*)d_in[4];
  const float* bias = (const float*)d_in[5];
  float* out = (float*)d_out;

  int n = in_sizes[0] / C;
  int E = in_sizes[1] / 2;
  int NB = (n + 127) / 128;           // buckets of 128 dst nodes (<=800)
  int chunk = (E + NBLK - 1) / NBLK;  // edges per partition block

  float* ws = (float*)d_ws;
  float* sums = ws;                      // 256 f
  float* scale = ws + 256;               // 128 f
  float* shift = ws + 384;               // 128 f
  float* dis = ws + 512;                 // n f
  int* btot = (int*)(ws + 512 + n);      // NB i
  int* boffs = btot + NB;                // NB+1 i
  int* noffs = boffs + NB + 1;           // n+1 i
  int* histG = noffs + n + 1;            // NBLK*NB i
  unsigned* binned = (unsigned*)(histG + (size_t)NBLK * NB);  // E u32
  unsigned* y = binned + E;              // n*64 u32 (bf16x2 rows)
  unsigned* ghi = y + (size_t)n * 64;    // n*64 u32
  unsigned* glo = ghi + (size_t)n * 64;  // n*64 u32

  size_t base = (size_t)512 + n + NB + (NB + 1) + (n + 1) +
                (size_t)NBLK * NB + E;
  size_t need_old = base + (size_t)n * 64;
  size_t need_new = base + (size_t)n * 64 * 3;
  int mode = (ws_size >= need_new * 4) ? 2 : (ws_size >= need_old * 4) ? 1 : 0;

  k_init<<<1, 256, 0, stream>>>(sums);
  k_stats<<<256, 256, 0, stream>>>((const float4*)x, sums, n);
  k_finalize<<<1, 128, 0, stream>>>(sums, gamma, beta, scale, shift, n);
  k_hist<<<NBLK, 256, 0, stream>>>(edge + E, histG, E, NB, chunk);
  k_scanH<<<NB, NBLK, 0, stream>>>(histG, btot, NB);
  k_scanB<<<1, 1024, 0, stream>>>(btot, boffs, NB, E);
  k_part<<<NBLK, 256, 0, stream>>>(edge, edge + E, histG, boffs, binned, E, NB, chunk);
  k_reorder<<<NB, 256, 0, stream>>>(binned, boffs, noffs, dis, n, E);
  if (mode >= 1) {
    k_prep<<<(n * 64 + 255) / 256, 256, 0, stream>>>(
        (const float2*)x, dis, (const float2*)scale, (const float2*)shift, y, n);
  }
  if (mode == 2) {
    k_G2<<<(n * 64 + 255) / 256, 256, 0, stream>>>(y, binned, noffs, dis,
                                                   ghi, glo, n);
    k_gemmM<<<(n + 63) / 64, 256, 0, stream>>>(ghi, glo, W, bias, out, n);
  } else {
    k_G<<<(n * 64 + 255) / 256, 256, 0, stream>>>(
        y, binned, noffs, dis, (const float2*)x, (const float2*)scale,
        (const float2*)shift, (float2*)out, n, mode);
    k_gemm<<<(n + 31) / 32, 256, 0, stream>>>(out, (const float4*)x, W, bias,
                                              scale, shift, dis, n);
  }
}